// Round 7
// baseline (168.695 us; speedup 1.0000x reference)
//
#include <hip/hip_runtime.h>

#define NEG_SLOPE 0.01f
#define CAP 64   // bucket capacity per dst; degrees ~Poisson(12), P(>=64) ~ 1e-24

typedef __attribute__((ext_vector_type(8))) short bf16x8;
typedef __attribute__((ext_vector_type(4))) float f32x4;

static __device__ __forceinline__ unsigned short f2bf(float f) {
  unsigned u = __float_as_uint(f);
  u += 0x7fffu + ((u >> 16) & 1u);   // round-to-nearest-even
  return (unsigned short)(u >> 16);
}

// ---------------- fused setup: zero counts | W->bf16 | p = W^T a -----------
__global__ __launch_bounds__(256) void k_setup(const float* __restrict__ W,
                                               const float* __restrict__ a,
                                               unsigned short* __restrict__ Wb,
                                               float* __restrict__ p_lo,
                                               float* __restrict__ p_hi,
                                               int* __restrict__ counts, int N, int nz) {
  int b = blockIdx.x;
  int t = threadIdx.x;
  if (b < nz) {
    int i = b * 256 + t;
    if (i < N) counts[i] = 0;
  } else if (b < nz + 64) {
    int i = (b - nz) * 256 + t;
    Wb[i] = f2bf(W[i]);
  } else {
    if (t < 128) {
      float lo = 0.f, hi = 0.f;
#pragma unroll 8
      for (int f = 0; f < 128; ++f) {
        float w = W[f * 128 + t];
        lo += w * a[f];
        hi += w * a[128 + f];
      }
      p_lo[t] = lo;
      p_hi[t] = hi;
    }
  }
}

// ------ fused: x -> bf16 A-frags (regs) + fp32 dots + MFMA -> msgs ---------
__global__ __launch_bounds__(256) void k_msg(const float* __restrict__ x,
                                             const float* __restrict__ p_lo,
                                             const float* __restrict__ p_hi,
                                             const unsigned short* __restrict__ Wb,
                                             unsigned short* __restrict__ msgs,
                                             float* __restrict__ s_src,
                                             float* __restrict__ s_dst, int N) {
  int wave = (blockIdx.x * 256 + threadIdx.x) >> 6;
  int lane = threadIdx.x & 63;
  int base = wave * 16;
  if (base >= N) return;
  int q = lane >> 4, r = lane & 15;
  int node = base + r;
  const float* xrow = x + (size_t)node * 128 + q * 8;
  const float4* pl = (const float4*)p_lo;
  const float4* ph = (const float4*)p_hi;
  bf16x8 afrag[4];
  float lo = 0.f, hi = 0.f;
#pragma unroll
  for (int c = 0; c < 4; ++c) {
    float4 v0 = *(const float4*)(xrow + c * 32);
    float4 v1 = *(const float4*)(xrow + c * 32 + 4);
    int fi = q * 2 + c * 8;
    float4 a0 = pl[fi], a1 = pl[fi + 1];
    float4 b0 = ph[fi], b1 = ph[fi + 1];
    lo += v0.x * a0.x + v0.y * a0.y + v0.z * a0.z + v0.w * a0.w
        + v1.x * a1.x + v1.y * a1.y + v1.z * a1.z + v1.w * a1.w;
    hi += v0.x * b0.x + v0.y * b0.y + v0.z * b0.z + v0.w * b0.w
        + v1.x * b1.x + v1.y * b1.y + v1.z * b1.z + v1.w * b1.w;
    bf16x8 f;
    f[0] = (short)f2bf(v0.x); f[1] = (short)f2bf(v0.y);
    f[2] = (short)f2bf(v0.z); f[3] = (short)f2bf(v0.w);
    f[4] = (short)f2bf(v1.x); f[5] = (short)f2bf(v1.y);
    f[6] = (short)f2bf(v1.z); f[7] = (short)f2bf(v1.w);
    afrag[c] = f;
  }
  lo += __shfl_xor(lo, 16); lo += __shfl_xor(lo, 32);
  hi += __shfl_xor(hi, 16); hi += __shfl_xor(hi, 32);
  if (q == 0) { s_src[node] = lo; s_dst[node] = hi; }
#pragma unroll
  for (int ft = 0; ft < 8; ++ft) {
    const unsigned short* wrow = Wb + (size_t)(ft * 16 + r) * 128 + q * 8;
    f32x4 acc = {0.f, 0.f, 0.f, 0.f};
#pragma unroll
    for (int c = 0; c < 4; ++c) {
      bf16x8 bfrag = *(const bf16x8*)(wrow + c * 32);
      acc = __builtin_amdgcn_mfma_f32_16x16x32_bf16(afrag[c], bfrag, acc, 0, 0, 0);
    }
#pragma unroll
    for (int rr = 0; rr < 4; ++rr) {
      int n2 = base + q * 4 + rr;
      msgs[(size_t)n2 * 128 + ft * 16 + r] = f2bf(acc[rr]);
    }
  }
}

// -------- scatter: src-only 4B NT stores (no write-allocate); 2 edges/thr --
__global__ __launch_bounds__(256) void k_scatter(const int* __restrict__ ei,
                                                 int* __restrict__ counts,
                                                 unsigned* __restrict__ edges, int E) {
  int e2 = blockIdx.x * 256 + threadIdx.x;
  int e = e2 * 2;
  if (e >= E) return;
  int s0 = __builtin_nontemporal_load(ei + e);
  int s1 = __builtin_nontemporal_load(ei + e + 1);
  int d0 = __builtin_nontemporal_load(ei + E + e);
  int d1 = __builtin_nontemporal_load(ei + E + e + 1);
  int pos0 = atomicAdd(&counts[d0], 1);
  if (pos0 < CAP)
    __builtin_nontemporal_store((unsigned)s0, edges + (size_t)d0 * CAP + pos0);
  if (e + 1 < E) {
    int pos1 = atomicAdd(&counts[d1], 1);
    if (pos1 < CAP)
      __builtin_nontemporal_store((unsigned)s1, edges + (size_t)d1 * CAP + pos1);
  }
}

// ------- one wave per dst node: 16 edges in flight (4 groups x unroll 4) ---
__global__ __launch_bounds__(256) void k_agg(const unsigned short* __restrict__ msgs,
                                             const int* __restrict__ counts,
                                             const unsigned* __restrict__ edges,
                                             const float* __restrict__ s_src,
                                             const float* __restrict__ s_dst,
                                             float* __restrict__ out, int N) {
  int wave = (blockIdx.x * 256 + threadIdx.x) >> 6;
  int lane = threadIdx.x & 63;
  if (wave >= N) return;
  int node = wave;
  int g = lane >> 4;
  int r = lane & 15;
  float sdn = s_dst[node];
  float zs = s_src[node] + sdn;
  zs = zs > 0.f ? zs : NEG_SLOPE * zs;
  float wself = expf(zs);
  float wg = (g == 0) ? wself : 0.f;
  float denom = wg;
  float acc[8];
  {
    const uint4* mrow = (const uint4*)(msgs + (size_t)node * 128);
    uint4 m = mrow[r];
    unsigned mm[4] = {m.x, m.y, m.z, m.w};
#pragma unroll
    for (int c = 0; c < 4; ++c) {
      acc[2 * c]     = wg * __uint_as_float(mm[c] << 16);
      acc[2 * c + 1] = wg * __uint_as_float(mm[c] & 0xffff0000u);
    }
  }
  int cnt = counts[node];
  cnt = cnt < CAP ? cnt : CAP;
  const unsigned* bucket = edges + (size_t)node * CAP;
  int nIter = (cnt + 15) >> 4;   // 16 edges per iteration
  for (int it = 0; it < nIter; ++it) {
    int kb = it * 16 + g;
    bool v[4];
    unsigned e[4];
    uint4 m[4];
    float ss[4];
#pragma unroll
    for (int u = 0; u < 4; ++u) {
      int k = kb + u * 4;
      v[u] = k < cnt;
      e[u] = bucket[v[u] ? k : 0];
    }
#pragma unroll
    for (int u = 0; u < 4; ++u)
      m[u] = ((const uint4*)(msgs + (size_t)e[u] * 128))[r];
#pragma unroll
    for (int u = 0; u < 4; ++u)
      ss[u] = s_src[e[u]];
#pragma unroll
    for (int u = 0; u < 4; ++u) {
      float z = ss[u] + sdn;
      z = z > 0.f ? z : NEG_SLOPE * z;
      float w = v[u] ? expf(z) : 0.f;
      unsigned mm[4] = {m[u].x, m[u].y, m[u].z, m[u].w};
#pragma unroll
      for (int c = 0; c < 4; ++c) {
        acc[2 * c]     += w * __uint_as_float(mm[c] << 16);
        acc[2 * c + 1] += w * __uint_as_float(mm[c] & 0xffff0000u);
      }
      denom += w;
    }
  }
#pragma unroll
  for (int mask = 16; mask < 64; mask <<= 1) {
#pragma unroll
    for (int j = 0; j < 8; ++j) acc[j] += __shfl_xor(acc[j], mask);
    denom += __shfl_xor(denom, mask);
  }
  if (g == 0) {
    float inv = 1.f / fmaxf(denom, 1e-12f);
    float4 o0 = {acc[0] * inv, acc[1] * inv, acc[2] * inv, acc[3] * inv};
    float4 o1 = {acc[4] * inv, acc[5] * inv, acc[6] * inv, acc[7] * inv};
    float4* orow = (float4*)(out + (size_t)node * 128);
    orow[r * 2] = o0;
    orow[r * 2 + 1] = o1;
  }
}

extern "C" void kernel_launch(void* const* d_in, const int* in_sizes, int n_in,
                              void* d_out, int out_size, void* d_ws, size_t ws_size,
                              hipStream_t stream) {
  const float* x = (const float*)d_in[0];
  const int* ei = (const int*)d_in[1];
  const float* W = (const float*)d_in[2];
  const float* a = (const float*)d_in[3];
  float* out = (float*)d_out;
  int N = in_sizes[0] / 128;
  int E = in_sizes[1] / 2;

  char* ws = (char*)d_ws;
  size_t off = 0;
  auto alloc = [&](size_t bytes) {
    off = (off + 255) & ~(size_t)255;
    void* p = ws + off;
    off += bytes;
    return p;
  };
  unsigned short* msgs = (unsigned short*)alloc((size_t)N * 128 * 2);
  float* s_src = (float*)alloc((size_t)N * 4);
  float* s_dst = (float*)alloc((size_t)N * 4);
  float* p_lo = (float*)alloc(512);
  float* p_hi = (float*)alloc(512);
  unsigned short* Wb = (unsigned short*)alloc(128 * 128 * 2);
  int* counts = (int*)alloc((size_t)N * 4);
  unsigned* edges = (unsigned*)alloc((size_t)N * CAP * 4);

  int nz = (N + 255) / 256;
  int waves = (N + 15) / 16;
  k_setup<<<nz + 64 + 1, 256, 0, stream>>>(W, a, Wb, p_lo, p_hi, counts, N, nz);
  k_scatter<<<((E + 1) / 2 + 255) / 256, 256, 0, stream>>>(ei, counts, edges, E);
  k_msg<<<(waves + 3) / 4, 256, 0, stream>>>(x, p_lo, p_hi, Wb, msgs, s_src, s_dst, N);
  k_agg<<<(N + 3) / 4, 256, 0, stream>>>(msgs, counts, edges, s_src, s_dst, out, N);
}

// Round 8
// 159.544 us; speedup vs baseline: 1.0574x; 1.0574x over previous
//
#include <hip/hip_runtime.h>

#define NEG_SLOPE 0.01f
#define CAP 64   // bucket capacity per dst; degrees ~Poisson(12), P(>=64) ~ 1e-24

typedef __attribute__((ext_vector_type(8))) short bf16x8;
typedef __attribute__((ext_vector_type(4))) float f32x4;

static __device__ __forceinline__ unsigned short f2bf(float f) {
  unsigned u = __float_as_uint(f);
  u += 0x7fffu + ((u >> 16) & 1u);   // round-to-nearest-even
  return (unsigned short)(u >> 16);
}

// ---------------- fused setup: zero counts | W->bf16 | p = W^T a -----------
__global__ __launch_bounds__(256) void k_setup(const float* __restrict__ W,
                                               const float* __restrict__ a,
                                               unsigned short* __restrict__ Wb,
                                               float* __restrict__ p_lo,
                                               float* __restrict__ p_hi,
                                               int* __restrict__ counts, int N, int nz) {
  int b = blockIdx.x;
  int t = threadIdx.x;
  if (b < nz) {
    int i = b * 256 + t;
    if (i < N) counts[i] = 0;
  } else if (b < nz + 64) {
    int i = (b - nz) * 256 + t;
    Wb[i] = f2bf(W[i]);
  } else {
    if (t < 128) {
      float lo = 0.f, hi = 0.f;
#pragma unroll 8
      for (int f = 0; f < 128; ++f) {
        float w = W[f * 128 + t];
        lo += w * a[f];
        hi += w * a[128 + f];
      }
      p_lo[t] = lo;
      p_hi[t] = hi;
    }
  }
}

// ---- fused worker: [0,SB) = edge scatter | [SB,..) = x->msgs + scores -----
// The two roles share no data, so scatter's atomic latency overlaps with
// msg's MFMA/stream work on other CUs inside a single dispatch.
__global__ __launch_bounds__(256) void k_work(const float* __restrict__ x,
                                              const float* __restrict__ p_lo,
                                              const float* __restrict__ p_hi,
                                              const unsigned short* __restrict__ Wb,
                                              unsigned short* __restrict__ msgs,
                                              float* __restrict__ s_src,
                                              float* __restrict__ s_dst, int N,
                                              const int* __restrict__ ei,
                                              int* __restrict__ counts,
                                              unsigned* __restrict__ edges, int E,
                                              int SB) {
  if ((int)blockIdx.x < SB) {
    // ---------------- scatter role: 2 edges/thread ----------------
    int e2 = blockIdx.x * 256 + threadIdx.x;
    int e = e2 * 2;
    if (e >= E) return;
    int2 srcp = *(const int2*)(ei + e);
    int2 dstp = *(const int2*)(ei + E + e);
    int pos0 = atomicAdd(&counts[dstp.x], 1);
    if (pos0 < CAP) edges[(size_t)dstp.x * CAP + pos0] = (unsigned)srcp.x;
    if (e + 1 < E) {
      int pos1 = atomicAdd(&counts[dstp.y], 1);
      if (pos1 < CAP) edges[(size_t)dstp.y * CAP + pos1] = (unsigned)srcp.y;
    }
    return;
  }
  // ---------------- msg role: bf16 frags + fp32 dots + MFMA ----------------
  int bb = blockIdx.x - SB;
  int wave = (bb * 256 + (int)threadIdx.x) >> 6;
  int lane = threadIdx.x & 63;
  int base = wave * 16;
  if (base >= N) return;
  int q = lane >> 4, r = lane & 15;
  int node = base + r;
  const float* xrow = x + (size_t)node * 128 + q * 8;
  const float4* pl = (const float4*)p_lo;
  const float4* ph = (const float4*)p_hi;
  bf16x8 afrag[4];
  float lo = 0.f, hi = 0.f;
#pragma unroll
  for (int c = 0; c < 4; ++c) {
    float4 v0 = *(const float4*)(xrow + c * 32);
    float4 v1 = *(const float4*)(xrow + c * 32 + 4);
    int fi = q * 2 + c * 8;
    float4 a0 = pl[fi], a1 = pl[fi + 1];
    float4 b0 = ph[fi], b1 = ph[fi + 1];
    lo += v0.x * a0.x + v0.y * a0.y + v0.z * a0.z + v0.w * a0.w
        + v1.x * a1.x + v1.y * a1.y + v1.z * a1.z + v1.w * a1.w;
    hi += v0.x * b0.x + v0.y * b0.y + v0.z * b0.z + v0.w * b0.w
        + v1.x * b1.x + v1.y * b1.y + v1.z * b1.z + v1.w * b1.w;
    bf16x8 f;
    f[0] = (short)f2bf(v0.x); f[1] = (short)f2bf(v0.y);
    f[2] = (short)f2bf(v0.z); f[3] = (short)f2bf(v0.w);
    f[4] = (short)f2bf(v1.x); f[5] = (short)f2bf(v1.y);
    f[6] = (short)f2bf(v1.z); f[7] = (short)f2bf(v1.w);
    afrag[c] = f;
  }
  lo += __shfl_xor(lo, 16); lo += __shfl_xor(lo, 32);
  hi += __shfl_xor(hi, 16); hi += __shfl_xor(hi, 32);
  if (q == 0) { s_src[node] = lo; s_dst[node] = hi; }
#pragma unroll
  for (int ft = 0; ft < 8; ++ft) {
    const unsigned short* wrow = Wb + (size_t)(ft * 16 + r) * 128 + q * 8;
    f32x4 acc = {0.f, 0.f, 0.f, 0.f};
#pragma unroll
    for (int c = 0; c < 4; ++c) {
      bf16x8 bfrag = *(const bf16x8*)(wrow + c * 32);
      acc = __builtin_amdgcn_mfma_f32_16x16x32_bf16(afrag[c], bfrag, acc, 0, 0, 0);
    }
#pragma unroll
    for (int rr = 0; rr < 4; ++rr) {
      int n2 = base + q * 4 + rr;
      msgs[(size_t)n2 * 128 + ft * 16 + r] = f2bf(acc[rr]);
    }
  }
}

// ------- one wave per dst node: 16 edges in flight (4 groups x unroll 4) ---
__global__ __launch_bounds__(256) void k_agg(const unsigned short* __restrict__ msgs,
                                             const int* __restrict__ counts,
                                             const unsigned* __restrict__ edges,
                                             const float* __restrict__ s_src,
                                             const float* __restrict__ s_dst,
                                             float* __restrict__ out, int N) {
  int wave = (blockIdx.x * 256 + threadIdx.x) >> 6;
  int lane = threadIdx.x & 63;
  if (wave >= N) return;
  int node = wave;
  int g = lane >> 4;
  int r = lane & 15;
  float sdn = s_dst[node];
  float zs = s_src[node] + sdn;
  zs = zs > 0.f ? zs : NEG_SLOPE * zs;
  float wself = expf(zs);
  float wg = (g == 0) ? wself : 0.f;
  float denom = wg;
  float acc[8];
  {
    const uint4* mrow = (const uint4*)(msgs + (size_t)node * 128);
    uint4 m = mrow[r];
    unsigned mm[4] = {m.x, m.y, m.z, m.w};
#pragma unroll
    for (int c = 0; c < 4; ++c) {
      acc[2 * c]     = wg * __uint_as_float(mm[c] << 16);
      acc[2 * c + 1] = wg * __uint_as_float(mm[c] & 0xffff0000u);
    }
  }
  int cnt = counts[node];
  cnt = cnt < CAP ? cnt : CAP;
  const unsigned* bucket = edges + (size_t)node * CAP;
  int nIter = (cnt + 15) >> 4;   // 16 edges per iteration
  for (int it = 0; it < nIter; ++it) {
    int kb = it * 16 + g;
    bool v[4];
    unsigned e[4];
    uint4 m[4];
    float ss[4];
#pragma unroll
    for (int u = 0; u < 4; ++u) {
      int k = kb + u * 4;
      v[u] = k < cnt;
      e[u] = bucket[v[u] ? k : 0];
    }
#pragma unroll
    for (int u = 0; u < 4; ++u)
      m[u] = ((const uint4*)(msgs + (size_t)e[u] * 128))[r];
#pragma unroll
    for (int u = 0; u < 4; ++u)
      ss[u] = s_src[e[u]];
#pragma unroll
    for (int u = 0; u < 4; ++u) {
      float z = ss[u] + sdn;
      z = z > 0.f ? z : NEG_SLOPE * z;
      float w = v[u] ? expf(z) : 0.f;
      unsigned mm[4] = {m[u].x, m[u].y, m[u].z, m[u].w};
#pragma unroll
      for (int c = 0; c < 4; ++c) {
        acc[2 * c]     += w * __uint_as_float(mm[c] << 16);
        acc[2 * c + 1] += w * __uint_as_float(mm[c] & 0xffff0000u);
      }
      denom += w;
    }
  }
#pragma unroll
  for (int mask = 16; mask < 64; mask <<= 1) {
#pragma unroll
    for (int j = 0; j < 8; ++j) acc[j] += __shfl_xor(acc[j], mask);
    denom += __shfl_xor(denom, mask);
  }
  if (g == 0) {
    float inv = 1.f / fmaxf(denom, 1e-12f);
    float4 o0 = {acc[0] * inv, acc[1] * inv, acc[2] * inv, acc[3] * inv};
    float4 o1 = {acc[4] * inv, acc[5] * inv, acc[6] * inv, acc[7] * inv};
    float4* orow = (float4*)(out + (size_t)node * 128);
    orow[r * 2] = o0;
    orow[r * 2 + 1] = o1;
  }
}

extern "C" void kernel_launch(void* const* d_in, const int* in_sizes, int n_in,
                              void* d_out, int out_size, void* d_ws, size_t ws_size,
                              hipStream_t stream) {
  const float* x = (const float*)d_in[0];
  const int* ei = (const int*)d_in[1];
  const float* W = (const float*)d_in[2];
  const float* a = (const float*)d_in[3];
  float* out = (float*)d_out;
  int N = in_sizes[0] / 128;
  int E = in_sizes[1] / 2;

  char* ws = (char*)d_ws;
  size_t off = 0;
  auto alloc = [&](size_t bytes) {
    off = (off + 255) & ~(size_t)255;
    void* p = ws + off;
    off += bytes;
    return p;
  };
  unsigned short* msgs = (unsigned short*)alloc((size_t)N * 128 * 2);
  float* s_src = (float*)alloc((size_t)N * 4);
  float* s_dst = (float*)alloc((size_t)N * 4);
  float* p_lo = (float*)alloc(512);
  float* p_hi = (float*)alloc(512);
  unsigned short* Wb = (unsigned short*)alloc(128 * 128 * 2);
  int* counts = (int*)alloc((size_t)N * 4);
  unsigned* edges = (unsigned*)alloc((size_t)N * CAP * 4);

  int nz = (N + 255) / 256;
  int waves = (N + 15) / 16;
  int SB = ((E + 1) / 2 + 255) / 256;           // scatter blocks
  int MB = (waves + 3) / 4;                     // msg blocks
  k_setup<<<nz + 64 + 1, 256, 0, stream>>>(W, a, Wb, p_lo, p_hi, counts, N, nz);
  k_work<<<SB + MB, 256, 0, stream>>>(x, p_lo, p_hi, Wb, msgs, s_src, s_dst, N,
                                      ei, counts, edges, E, SB);
  k_agg<<<(N + 3) / 4, 256, 0, stream>>>(msgs, counts, edges, s_src, s_dst, out, N);
}